// Round 5
// baseline (4259.483 us; speedup 1.0000x reference)
//
#include <hip/hip_runtime.h>
#include <hip/hip_bf16.h>

// Problem constants (fixed by the harness).
#define N_B   128     // batch
#define L_SEQ 2048    // sequence length
#define H_DIM 256     // hidden
#define EMB   256     // embedding dim
#define G3    768     // 3 used gates (F, O, Htmp) * 256
#define G4    1024    // total gate rows
#define WROW  512     // W_w row length (H + Emb), C-order rows
#define V_SZ  32000   // vocab

// R17: r12/r15/r16 invariant — 2.8-3.0ms regardless of split/fences; the
// allocator always targets >=4 waves/SIMD (VGPR 64-128) and round-trips
// ~393KB/CU/step of weights through scratch/L1 (~3300 cyc/step, matches).
// waves_per_eu(2,2)/(4,4) set a budget the allocator may undershoot — and
// it always does. The untried config: 256-thread block (4 waves = 1
// wave/SIMD) + amdgpu_waves_per_eu(1,1) => budget is the FULL 512
// VGPRs/wave (m08: no spill through 450). Thread j owns ALL of k for its
// 3 gate rows: 384 weight dwords + ~30 scalars ~= 415 < 450. Structural
// bonuses: no k-split -> no pbuf, ONE barrier/step, epilogue on all
// threads. Model if resident: ~580 VALU*2cy + ~350 latency ~= 1500
// cyc/step -> ~1.3ms. Mega-fences kept (un-sinkable, opaque values).

typedef unsigned short ushort_t;
typedef unsigned int   uint_t;

using f32x4  = __attribute__((ext_vector_type(4))) float;
using bf16x8 = __attribute__((ext_vector_type(8))) short;
using h2_t   = __attribute__((ext_vector_type(2))) _Float16;
using ushort4_t = __attribute__((ext_vector_type(4))) ushort_t;
using u32x4  = __attribute__((ext_vector_type(4))) uint_t;

__device__ __forceinline__ float bf2f(ushort_t u) {
  union { uint_t u; float f; } x; x.u = ((uint_t)u) << 16; return x.f;
}
__device__ __forceinline__ ushort_t f2bf(float f) {  // RNE f32 -> bf16
  union { float f; uint_t u; } x; x.f = f;
  return (ushort_t)((x.u + 0x7fffu + ((x.u >> 16) & 1u)) >> 16);
}
__device__ __forceinline__ float rcp_f(float x) {
#if __has_builtin(__builtin_amdgcn_rcpf)
  return __builtin_amdgcn_rcpf(x);
#else
  return 1.0f / x;
#endif
}
__device__ __forceinline__ float clampf(float x, float lo, float hi) {
  return fminf(fmaxf(x, lo), hi);
}
__device__ __forceinline__ float sigmoid_f(float x) {
  x = clampf(x, -30.f, 30.f);
  return rcp_f(1.0f + __expf(-x));
}
__device__ __forceinline__ float tanh_f(float x) {
  x = clampf(x, -15.f, 15.f);   // exact: tanh saturates well before 15
  float e = __expf(-2.0f * x);
  return (1.0f - e) * rcp_f(1.0f + e);
}
__device__ __forceinline__ float fdot2_f(h2_t a, h2_t b, float c) {
#if __has_builtin(__builtin_amdgcn_fdot2)
  return __builtin_amdgcn_fdot2(a, b, c, false);
#else
  return c + (float)a.x * (float)b.x + (float)a.y * (float)b.y;
#endif
}
__device__ __forceinline__ uint_t lane_bcast(uint_t v, int l) {
#if __has_builtin(__builtin_amdgcn_readlane)
  return (uint_t)__builtin_amdgcn_readlane((int)v, l);
#else
  return (uint_t)__shfl((int)v, l, 64);
#endif
}
// bf16 pair (packed dword, little-endian) -> f16 pair (exact for normal range)
__device__ __forceinline__ h2_t bfpair_to_h2(uint_t u) {
  union { uint_t u; float f; } lo, hi;
  lo.u = u << 16;
  hi.u = u & 0xffff0000u;
  h2_t r; r.x = (_Float16)lo.f; r.y = (_Float16)hi.f; return r;
}

// gate col g in [0,768) -> W_w row: F=g, O=512+(g-256), T=768+(g-512)
__device__ __forceinline__ int gmap(int g) { return (g < 256) ? g : g + 256; }

// Single volatile asm, 32 "+v" outputs: un-sinkable, un-splittable; forces
// all 32 values simultaneously VGPR-resident and opaque thereafter.
#define FENCE_W32(A) asm volatile("" :                                        \
  "+v"((A)[0]),  "+v"((A)[1]),  "+v"((A)[2]),  "+v"((A)[3]),                  \
  "+v"((A)[4]),  "+v"((A)[5]),  "+v"((A)[6]),  "+v"((A)[7]),                  \
  "+v"((A)[8]),  "+v"((A)[9]),  "+v"((A)[10]), "+v"((A)[11]),                 \
  "+v"((A)[12]), "+v"((A)[13]), "+v"((A)[14]), "+v"((A)[15]),                 \
  "+v"((A)[16]), "+v"((A)[17]), "+v"((A)[18]), "+v"((A)[19]),                 \
  "+v"((A)[20]), "+v"((A)[21]), "+v"((A)[22]), "+v"((A)[23]),                 \
  "+v"((A)[24]), "+v"((A)[25]), "+v"((A)[26]), "+v"((A)[27]),                 \
  "+v"((A)[28]), "+v"((A)[29]), "+v"((A)[30]), "+v"((A)[31]))

// ---------------------------------------------------------------------------
// Phase 0: dtype probe (validated: r11..r16 passed using these flags).
// ---------------------------------------------------------------------------
__global__ void dtype_probe(const uint_t* __restrict__ Ed,
                            const uint_t* __restrict__ Xd,
                            const uint_t* __restrict__ Wd,
                            uint_t* __restrict__ flags) {
  if (threadIdx.x != 0 || blockIdx.x != 0) return;
  int saneE = 0, saneW = 0;
  for (int i = 0; i < 256; ++i) {
    uint_t le = Ed[i] & 0xffffu, ee = (le >> 7) & 0xffu;
    if (ee == 0u || (ee >= 90u && ee <= 126u)) saneE++;
    uint_t lw = Wd[i] & 0xffffu, ew = (lw >> 7) & 0xffu;
    if (ew == 0u || (ew >= 90u && ew <= 126u)) saneW++;
  }
  uint_t nz = 0u;
  for (int i = 0; i < 128; ++i) nz |= Xd[2 * i + 1];
  flags[0] = (saneE < 192) ? 1u : 0u;   // 1 = f32
  flags[1] = (nz == 0u) ? 1u : 0u;      // 1 = int64
  flags[2] = (saneW < 192) ? 1u : 0u;   // 1 = f32
}

// ---------------------------------------------------------------------------
// Phase 1: Eg[v, g] = sum_k E[v,k] * W_w[gmap(g), 256+k] + W_b[gmap(g)]
// (unchanged from r11 — verified end-to-end, ~tens of µs)
// ---------------------------------------------------------------------------
__global__ __launch_bounds__(256) void eg_gemm(const void* __restrict__ Ein,
                                               const void* __restrict__ Wwin,
                                               const void* __restrict__ Wbin,
                                               _Float16* __restrict__ Eg,
                                               const uint_t* __restrict__ flags) {
  __shared__ __align__(16) ushort_t At[16][264];  // 16 x (256+8 pad) bf16
  const int tid = threadIdx.x;
  const int v0  = blockIdx.x * 16;
  const uint_t ef32 = flags[0];
  const uint_t wf32 = flags[2];

  if (!ef32) {
    const ushort_t* E = (const ushort_t*)Ein;
#pragma unroll
    for (int i = 0; i < 2; ++i) {
      int idx = tid + i * 256;           // 0..511
      int row = idx >> 5, seg = idx & 31;
      const uint4* src = (const uint4*)(E + (size_t)(v0 + row) * EMB + seg * 8);
      *(uint4*)&At[row][seg * 8] = *src;
    }
  } else {
    const float* Ef = (const float*)Ein;
#pragma unroll
    for (int i = 0; i < 4; ++i) {
      int idx = tid + i * 256;           // 0..1023
      int row = idx >> 6, seg = idx & 63;
      float4 v = *(const float4*)(Ef + (size_t)(v0 + row) * EMB + seg * 4);
      ushort4_t s;
      s.x = f2bf(v.x); s.y = f2bf(v.y); s.z = f2bf(v.z); s.w = f2bf(v.w);
      *(ushort4_t*)&At[row][seg * 4] = s;
    }
  }
  __syncthreads();

  const int lane = tid & 63, wv = tid >> 6;
  const int m = lane & 15, q = lane >> 4;

  f32x4 acc[12];
#pragma unroll
  for (int nt = 0; nt < 12; ++nt) acc[nt] = f32x4{0.f, 0.f, 0.f, 0.f};

  if (!wf32) {
    const ushort_t* Ww = (const ushort_t*)Wwin;
#pragma unroll
    for (int kt = 0; kt < 8; ++kt) {
      bf16x8 a = *(const bf16x8*)&At[m][kt * 32 + q * 8];
#pragma unroll
      for (int nt = 0; nt < 12; ++nt) {
        int g  = wv * 192 + nt * 16 + m;
        int gr = gmap(g);
        const bf16x8* bp =
            (const bf16x8*)(Ww + (size_t)gr * WROW + EMB + kt * 32 + q * 8);
        acc[nt] = __builtin_amdgcn_mfma_f32_16x16x32_bf16(a, *bp, acc[nt], 0, 0, 0);
      }
    }
  } else {
    const float* Wf = (const float*)Wwin;
#pragma unroll
    for (int kt = 0; kt < 8; ++kt) {
      bf16x8 a = *(const bf16x8*)&At[m][kt * 32 + q * 8];
#pragma unroll
      for (int nt = 0; nt < 12; ++nt) {
        int g  = wv * 192 + nt * 16 + m;
        int gr = gmap(g);
        const float* wp = Wf + (size_t)gr * WROW + EMB + kt * 32 + q * 8;
        float4 w0 = *(const float4*)(wp);
        float4 w1 = *(const float4*)(wp + 4);
        bf16x8 b;
        b[0] = (short)f2bf(w0.x); b[1] = (short)f2bf(w0.y);
        b[2] = (short)f2bf(w0.z); b[3] = (short)f2bf(w0.w);
        b[4] = (short)f2bf(w1.x); b[5] = (short)f2bf(w1.y);
        b[6] = (short)f2bf(w1.z); b[7] = (short)f2bf(w1.w);
        acc[nt] = __builtin_amdgcn_mfma_f32_16x16x32_bf16(a, b, acc[nt], 0, 0, 0);
      }
    }
  }

#pragma unroll
  for (int nt = 0; nt < 12; ++nt) {
    int g  = wv * 192 + nt * 16 + m;
    int gr = gmap(g);
    float bias = wf32 ? ((const float*)Wbin)[gr] : bf2f(((const ushort_t*)Wbin)[gr]);
#pragma unroll
    for (int j = 0; j < 4; ++j) {
      int v = v0 + q * 4 + j;
      Eg[(size_t)v * G3 + g] = (_Float16)(acc[nt][j] + bias);
    }
  }
}

// ---------------------------------------------------------------------------
// Phase 2 (R17): recurrence, 256 threads/block (4 waves = 1 wave/SIMD),
// NO k-split. Thread j owns rows {j, 512+j, 768+j}, FULL k in registers:
// wF/wO/wT[128] f16-pair dwords (384 total). waves_per_eu(1,1) => 512-VGPR
// budget. Per step: ONE barrier; h broadcast via 2 lane-held dwords +
// readlane; per-thread epilogue (no pbuf, no idle quarters).
// ---------------------------------------------------------------------------
__global__
__attribute__((amdgpu_flat_work_group_size(256, 256), amdgpu_waves_per_eu(1, 1)))
void lstm_rec(const int* __restrict__ Xi,
              const void* __restrict__ Wwin,
              const _Float16* __restrict__ Eg,
              float* __restrict__ out,
              const uint_t* __restrict__ flags) {
  __shared__ uint_t hbuf[2][128];        // h as 256 f16 = 128 dwords, x2 buf
  const int tid  = threadIdx.x;          // 0..255
  const int lane = tid & 63;
  const int j    = tid;                  // hidden column
  const int n    = blockIdx.x;
  const uint_t wf32 = flags[2];
  const uint_t x64  = flags[1];

  // 384 weight dwords per thread (128 per gate), full k = 0..255.
  uint_t wF[128], wO[128], wT[128];
  if (!wf32) {
    const ushort_t* Wb16 = (const ushort_t*)Wwin;
    const u32x4* sF = (const u32x4*)(Wb16 + (size_t)(j)       * WROW);
    const u32x4* sO = (const u32x4*)(Wb16 + (size_t)(512 + j) * WROW);
    const u32x4* sT = (const u32x4*)(Wb16 + (size_t)(768 + j) * WROW);
#pragma unroll
    for (int i = 0; i < 32; ++i) {
      u32x4 vF = sF[i], vO = sO[i], vT = sT[i];
#pragma unroll
      for (int c4 = 0; c4 < 4; ++c4) {
        wF[i * 4 + c4] = __builtin_bit_cast(uint_t, bfpair_to_h2(vF[c4]));
        wO[i * 4 + c4] = __builtin_bit_cast(uint_t, bfpair_to_h2(vO[c4]));
        wT[i * 4 + c4] = __builtin_bit_cast(uint_t, bfpair_to_h2(vT[c4]));
      }
    }
  } else {
    const float* Wf = (const float*)Wwin;
    const float* sF = Wf + (size_t)(j)       * WROW;
    const float* sO = Wf + (size_t)(512 + j) * WROW;
    const float* sT = Wf + (size_t)(768 + j) * WROW;
#pragma unroll
    for (int dd = 0; dd < 128; ++dd) {
      float2 vF = *(const float2*)(sF + 2 * dd);
      float2 vO = *(const float2*)(sO + 2 * dd);
      float2 vT = *(const float2*)(sT + 2 * dd);
      h2_t pF, pO, pT;
      pF.x = (_Float16)vF.x; pF.y = (_Float16)vF.y;   // RNE, = r12..r16
      pO.x = (_Float16)vO.x; pO.y = (_Float16)vO.y;
      pT.x = (_Float16)vT.x; pT.y = (_Float16)vT.y;
      wF[dd] = __builtin_bit_cast(uint_t, pF);
      wO[dd] = __builtin_bit_cast(uint_t, pO);
      wT[dd] = __builtin_bit_cast(uint_t, pT);
    }
  }
  // Mega-fences: volatile, 32 outputs each — un-sinkable, opaque values.
  FENCE_W32(wF);      FENCE_W32(wF + 32); FENCE_W32(wF + 64); FENCE_W32(wF + 96);
  FENCE_W32(wO);      FENCE_W32(wO + 32); FENCE_W32(wO + 64); FENCE_W32(wO + 96);
  FENCE_W32(wT);      FENCE_W32(wT + 32); FENCE_W32(wT + 64); FENCE_W32(wT + 96);

  if (tid < 128) hbuf[0][tid] = 0u;  // h_0 = 0

  float c = 0.f, hlast = 0.f;
  const size_t xbase = (size_t)n * L_SEQ;

  // px(t=0), all threads.
  float pxF, pxO, pxT;
  {
    int tok0 = x64 ? Xi[xbase * 2] : Xi[xbase];
    if ((uint_t)tok0 >= (uint_t)V_SZ) tok0 = 0;
    const _Float16* e = Eg + (size_t)tok0 * G3 + j;
    pxF = (float)e[0]; pxO = (float)e[256]; pxT = (float)e[512];
  }

  int cur = 0;
  for (int t = 0; t < L_SEQ; ++t) {
    __syncthreads();  // h(t) in hbuf[cur] published (prev iter's writes)

    const uint_t hva = hbuf[cur][lane];        // h dwords 0..63
    const uint_t hvb = hbuf[cur][64 + lane];   // h dwords 64..127

    // Prefetch px(t+1), hidden behind the dot phase.
    float nF, nO, nT;
    {
      int tp = (t + 1 < L_SEQ) ? (t + 1) : (L_SEQ - 1);
      int tok = x64 ? Xi[(xbase + tp) * 2] : Xi[xbase + tp];
      if ((uint_t)tok >= (uint_t)V_SZ) tok = 0;
      const _Float16* e = Eg + (size_t)tok * G3 + j;
      nF = (float)e[0]; nO = (float)e[256]; nT = (float)e[512];
    }

    float aF0 = 0.f, aO0 = 0.f, aT0 = 0.f;
    float aF1 = 0.f, aO1 = 0.f, aT1 = 0.f;
#pragma unroll
    for (int d = 0; d < 64; ++d) {
      h2_t hh = __builtin_bit_cast(h2_t, lane_bcast(hva, d));
      h2_t wf = __builtin_bit_cast(h2_t, wF[d]);
      h2_t wo = __builtin_bit_cast(h2_t, wO[d]);
      h2_t wt = __builtin_bit_cast(h2_t, wT[d]);
      if (d & 1) {
        aF1 = fdot2_f(wf, hh, aF1);
        aO1 = fdot2_f(wo, hh, aO1);
        aT1 = fdot2_f(wt, hh, aT1);
      } else {
        aF0 = fdot2_f(wf, hh, aF0);
        aO0 = fdot2_f(wo, hh, aO0);
        aT0 = fdot2_f(wt, hh, aT0);
      }
    }
#pragma unroll
    for (int d = 0; d < 64; ++d) {
      h2_t hh = __builtin_bit_cast(h2_t, lane_bcast(hvb, d));
      h2_t wf = __builtin_bit_cast(h2_t, wF[64 + d]);
      h2_t wo = __builtin_bit_cast(h2_t, wO[64 + d]);
      h2_t wt = __builtin_bit_cast(h2_t, wT[64 + d]);
      if (d & 1) {
        aF1 = fdot2_f(wf, hh, aF1);
        aO1 = fdot2_f(wo, hh, aO1);
        aT1 = fdot2_f(wt, hh, aT1);
      } else {
        aF0 = fdot2_f(wf, hh, aF0);
        aO0 = fdot2_f(wo, hh, aO0);
        aT0 = fdot2_f(wt, hh, aT0);
      }
    }
    float aF = aF0 + aF1 + pxF;
    float aO = aO0 + aO1 + pxO;
    float aT = aT0 + aT1 + pxT;

    float Fg = sigmoid_f(aF);
    float Og = sigmoid_f(aO);
    float Tg = tanh_f(aT);
    c = Fg * c + Og * Tg;          // faithful to ref: uses O-gate, not I-gate
    float hv2 = Og * tanh_f(c);
    hlast = hv2;
    ((_Float16*)hbuf[cur ^ 1])[j] = (_Float16)hv2;   // publish h(t+1)
    pxF = nF; pxO = nO; pxT = nT;
    cur ^= 1;
  }

  // FLOAT32 output, C-order (n, j).
  out[(size_t)n * H_DIM + j] = hlast;
}

extern "C" void kernel_launch(void* const* d_in, const int* in_sizes, int n_in,
                              void* d_out, int out_size, void* d_ws, size_t ws_size,
                              hipStream_t stream) {
  const void* X  = d_in[0];
  const void* E  = d_in[1];
  const void* Ww = d_in[2];
  const void* Wb = d_in[3];
  for (int i = 0; i < n_in && i < 4; ++i) {
    switch (in_sizes[i]) {
      case N_B * L_SEQ: X  = d_in[i]; break;   // 262144
      case V_SZ * EMB:  E  = d_in[i]; break;   // 8192000
      case G4 * WROW:   Ww = d_in[i]; break;   // 524288
      case G4:          Wb = d_in[i]; break;   // 1024
      default: break;
    }
  }
  float* out = (float*)d_out;

  // ws: [0,256) flags | [256, ...) Eg (32000*768 f16 = 46.9 MiB). (= r12)
  uint_t*   flags = (uint_t*)d_ws;
  _Float16* Eg    = (_Float16*)((char*)d_ws + 256);

  dtype_probe<<<dim3(1), dim3(64), 0, stream>>>(
      (const uint_t*)E, (const uint_t*)X, (const uint_t*)Ww, flags);
  eg_gemm<<<dim3(V_SZ / 16), dim3(256), 0, stream>>>(E, Ww, Wb, Eg, flags);
  lstm_rec<<<dim3(N_B), dim3(256), 0, stream>>>((const int*)X, Ww, Eg, out, flags);
}

// Round 7
// 3360.487 us; speedup vs baseline: 1.2675x; 1.2675x over previous
//
#include <hip/hip_runtime.h>
#include <hip/hip_bf16.h>

// Problem constants (fixed by the harness).
#define N_B   128     // batch
#define L_SEQ 2048    // sequence length
#define H_DIM 256     // hidden
#define EMB   256     // embedding dim
#define G3    768     // 3 used gates (F, O, Htmp) * 256
#define G4    1024    // total gate rows
#define WROW  512     // W_w row length (H + Emb), C-order rows
#define V_SZ  32000   // vocab

// R19: re-framing from r12..r18 evidence.
// (1) 128 independent sequences on 256 CUs -> each block owns a CU; the
//     kernel is per-step LATENCY bound. 2.8ms = 2048 x ~3300cy steps, the
//     step dominated by the VALU issue stream: ~96k wave MACs (fdot2) +
//     ~same in accvgpr_read (weights AGPR-parked by the allocator; r16:
//     WRITE tiny + FETCH flat + VGPR 64 => on-chip, paid per use) +
//     readlane. Batching n/block lengthens steps -> wrong lever (r15/r16).
// (2) Fix: move the 196,608 MACs/step to the MATRIX pipe: 48 M-tiles x
//     8 K-tiles of mfma_f32_16x16x32_f16 = 384 MFMA/block-step (48/wave,
//     ~250-500cy). MFMA reads A-operands from AGPR natively, so the
//     allocator's AGPR-parking of the 192 fenced weight dwords becomes
//     FREE (no accvgpr_read per use). r16's un-sinkable mega-fence now
//     composes with the HW instead of fighting it.
// (3) r13/r18 both failed bit-identically consuming a ws weight table
//     (mechanism unexplained; Eg through the same ws works) -> NO ws
//     weight table: A-fragments load directly from Wwin in the preamble.
//     ws layout = r12's proven {flags@0 | Eg@+256}.
// Layouts copied from the WORKING eg_gemm below: A lane l holds
// A[row=l&15][k=(l>>4)*8+e] (bf16x8/f16x8 contiguous in k); B lane l holds
// B[k=(l>>4)*8+e][col=l&15]; D col=l&15, row=(l>>4)*4+reg (m89-verified).
// B is built as a broadcast of h (all 16 cols = same h) -> every D col
// equals G; no masking needed. All-f16 numerics = r12..r17's exactly.

typedef unsigned short ushort_t;
typedef unsigned int   uint_t;

using f32x4  = __attribute__((ext_vector_type(4))) float;
using bf16x8 = __attribute__((ext_vector_type(8))) short;
using h2_t   = __attribute__((ext_vector_type(2))) _Float16;
using f16x8  = __attribute__((ext_vector_type(8))) _Float16;
using ushort4_t = __attribute__((ext_vector_type(4))) ushort_t;
using u32x4  = __attribute__((ext_vector_type(4))) uint_t;

__device__ __forceinline__ float bf2f(ushort_t u) {
  union { uint_t u; float f; } x; x.u = ((uint_t)u) << 16; return x.f;
}
__device__ __forceinline__ ushort_t f2bf(float f) {  // RNE f32 -> bf16
  union { float f; uint_t u; } x; x.f = f;
  return (ushort_t)((x.u + 0x7fffu + ((x.u >> 16) & 1u)) >> 16);
}
__device__ __forceinline__ float rcp_f(float x) {
#if __has_builtin(__builtin_amdgcn_rcpf)
  return __builtin_amdgcn_rcpf(x);
#else
  return 1.0f / x;
#endif
}
__device__ __forceinline__ float clampf(float x, float lo, float hi) {
  return fminf(fmaxf(x, lo), hi);
}
__device__ __forceinline__ float sigmoid_f(float x) {
  x = clampf(x, -30.f, 30.f);
  return rcp_f(1.0f + __expf(-x));
}
__device__ __forceinline__ float tanh_f(float x) {
  x = clampf(x, -15.f, 15.f);   // exact: tanh saturates well before 15
  float e = __expf(-2.0f * x);
  return (1.0f - e) * rcp_f(1.0f + e);
}
// bf16 pair (packed dword, little-endian) -> f16 pair (exact for normal range)
__device__ __forceinline__ h2_t bfpair_to_h2(uint_t u) {
  union { uint_t u; float f; } lo, hi;
  lo.u = u << 16;
  hi.u = u & 0xffff0000u;
  h2_t r; r.x = (_Float16)lo.f; r.y = (_Float16)hi.f; return r;
}

// gate col g in [0,768) -> W_w row: F=g, O=512+(g-256), T=768+(g-512)
__device__ __forceinline__ int gmap(int g) { return (g < 256) ? g : g + 256; }

// Volatile fence over 8 x u32x4 (32 dwords): un-sinkable, un-splittable;
// forces simultaneous on-chip residency; values opaque (no remat). With
// MFMA consumers, AGPR-parking these is free (native AGPR A-operands).
#define FENCE_V8(A) asm volatile("" :                                         \
  "+v"((A)[0]), "+v"((A)[1]), "+v"((A)[2]), "+v"((A)[3]),                     \
  "+v"((A)[4]), "+v"((A)[5]), "+v"((A)[6]), "+v"((A)[7]))

// ---------------------------------------------------------------------------
// Phase 0: dtype probe (validated: r11..r17 passed using these flags).
// ---------------------------------------------------------------------------
__global__ void dtype_probe(const uint_t* __restrict__ Ed,
                            const uint_t* __restrict__ Xd,
                            const uint_t* __restrict__ Wd,
                            uint_t* __restrict__ flags) {
  if (threadIdx.x != 0 || blockIdx.x != 0) return;
  int saneE = 0, saneW = 0;
  for (int i = 0; i < 256; ++i) {
    uint_t le = Ed[i] & 0xffffu, ee = (le >> 7) & 0xffu;
    if (ee == 0u || (ee >= 90u && ee <= 126u)) saneE++;
    uint_t lw = Wd[i] & 0xffffu, ew = (lw >> 7) & 0xffu;
    if (ew == 0u || (ew >= 90u && ew <= 126u)) saneW++;
  }
  uint_t nz = 0u;
  for (int i = 0; i < 128; ++i) nz |= Xd[2 * i + 1];
  flags[0] = (saneE < 192) ? 1u : 0u;   // 1 = f32
  flags[1] = (nz == 0u) ? 1u : 0u;      // 1 = int64
  flags[2] = (saneW < 192) ? 1u : 0u;   // 1 = f32
}

// ---------------------------------------------------------------------------
// Phase 1: Eg[v, g] = sum_k E[v,k] * W_w[gmap(g), 256+k] + W_b[gmap(g)]
// (unchanged from r11 — verified end-to-end, ~tens of µs)
// ---------------------------------------------------------------------------
__global__ __launch_bounds__(256) void eg_gemm(const void* __restrict__ Ein,
                                               const void* __restrict__ Wwin,
                                               const void* __restrict__ Wbin,
                                               _Float16* __restrict__ Eg,
                                               const uint_t* __restrict__ flags) {
  __shared__ __align__(16) ushort_t At[16][264];  // 16 x (256+8 pad) bf16
  const int tid = threadIdx.x;
  const int v0  = blockIdx.x * 16;
  const uint_t ef32 = flags[0];
  const uint_t wf32 = flags[2];

  if (!ef32) {
    const ushort_t* E = (const ushort_t*)Ein;
#pragma unroll
    for (int i = 0; i < 2; ++i) {
      int idx = tid + i * 256;           // 0..511
      int row = idx >> 5, seg = idx & 31;
      const uint4* src = (const uint4*)(E + (size_t)(v0 + row) * EMB + seg * 8);
      *(uint4*)&At[row][seg * 8] = *src;
    }
  } else {
    const float* Ef = (const float*)Ein;
#pragma unroll
    for (int i = 0; i < 4; ++i) {
      int idx = tid + i * 256;           // 0..1023
      int row = idx >> 6, seg = idx & 63;
      float4 v = *(const float4*)(Ef + (size_t)(v0 + row) * EMB + seg * 4);
      ushort4_t s;
      s.x = f2bf(v.x); s.y = f2bf(v.y); s.z = f2bf(v.z); s.w = f2bf(v.w);
      *(ushort4_t*)&At[row][seg * 4] = s;
    }
  }
  __syncthreads();

  const int lane = tid & 63, wv = tid >> 6;
  const int m = lane & 15, q = lane >> 4;

  f32x4 acc[12];
#pragma unroll
  for (int nt = 0; nt < 12; ++nt) acc[nt] = f32x4{0.f, 0.f, 0.f, 0.f};

  if (!wf32) {
    const ushort_t* Ww = (const ushort_t*)Wwin;
#pragma unroll
    for (int kt = 0; kt < 8; ++kt) {
      bf16x8 a = *(const bf16x8*)&At[m][kt * 32 + q * 8];
#pragma unroll
      for (int nt = 0; nt < 12; ++nt) {
        int g  = wv * 192 + nt * 16 + m;
        int gr = gmap(g);
        const bf16x8* bp =
            (const bf16x8*)(Ww + (size_t)gr * WROW + EMB + kt * 32 + q * 8);
        acc[nt] = __builtin_amdgcn_mfma_f32_16x16x32_bf16(a, *bp, acc[nt], 0, 0, 0);
      }
    }
  } else {
    const float* Wf = (const float*)Wwin;
#pragma unroll
    for (int kt = 0; kt < 8; ++kt) {
      bf16x8 a = *(const bf16x8*)&At[m][kt * 32 + q * 8];
#pragma unroll
      for (int nt = 0; nt < 12; ++nt) {
        int g  = wv * 192 + nt * 16 + m;
        int gr = gmap(g);
        const float* wp = Wf + (size_t)gr * WROW + EMB + kt * 32 + q * 8;
        float4 w0 = *(const float4*)(wp);
        float4 w1 = *(const float4*)(wp + 4);
        bf16x8 b;
        b[0] = (short)f2bf(w0.x); b[1] = (short)f2bf(w0.y);
        b[2] = (short)f2bf(w0.z); b[3] = (short)f2bf(w0.w);
        b[4] = (short)f2bf(w1.x); b[5] = (short)f2bf(w1.y);
        b[6] = (short)f2bf(w1.z); b[7] = (short)f2bf(w1.w);
        acc[nt] = __builtin_amdgcn_mfma_f32_16x16x32_bf16(a, b, acc[nt], 0, 0, 0);
      }
    }
  }

#pragma unroll
  for (int nt = 0; nt < 12; ++nt) {
    int g  = wv * 192 + nt * 16 + m;
    int gr = gmap(g);
    float bias = wf32 ? ((const float*)Wbin)[gr] : bf2f(((const ushort_t*)Wbin)[gr]);
#pragma unroll
    for (int j = 0; j < 4; ++j) {
      int v = v0 + q * 4 + j;
      Eg[(size_t)v * G3 + g] = (_Float16)(acc[nt][j] + bias);
    }
  }
}

// ---------------------------------------------------------------------------
// Phase 2 (R19): recurrence via MFMA. 512 threads (8 waves), 1 n per block.
// Per step: G[768] = W_h[768x256] (f16, register/AGPR-resident A-frags) x
// h[256] (f16, LDS-broadcast B-frags). Wave w owns M-tiles 6w..6w+5.
// 48 mfma_f32_16x16x32_f16 per wave per step; D col=lane&15 (all cols
// equal G), row=(lane>>4)*4+reg. Lanes with (lane&15)==0 store G to LDS;
// threads 0..255 run the gate/c/h epilogue. Two barriers per step.
// ---------------------------------------------------------------------------
__global__ __launch_bounds__(512)
void lstm_rec_mfma(const int* __restrict__ Xi,
                   const void* __restrict__ Wwin,
                   const _Float16* __restrict__ Eg,
                   float* __restrict__ out,
                   const uint_t* __restrict__ flags) {
  __shared__ __align__(16) _Float16 hbuf[2][256];  // h(t) as f16
  __shared__ __align__(16) float    Gbuf[G3];      // per-step gate pre-acts
  const int tid  = threadIdx.x;          // 0..511
  const int lane = tid & 63;
  const int w    = tid >> 6;             // wave 0..7
  const int q    = lane >> 4;            // k-chunk / D-row group
  const int rr   = lane & 15;            // A row within tile
  const int n    = blockIdx.x;
  const uint_t wf32 = flags[2];
  const uint_t x64  = flags[1];

  // ---- Preamble: load 48 A-fragments (f16) DIRECTLY from Wwin. ----
  // Frag (m,kt): lane holds W[(w*6+m)*16 + rr][kt*32 + q*8 .. +7] as f16x8.
  // Conversions identical to r12..r17 (bf16->f16 exact; f32->f16 RNE).
  u32x4 wAq[48];
  if (!wf32) {
    const ushort_t* Wb16 = (const ushort_t*)Wwin;
#pragma unroll
    for (int m = 0; m < 6; ++m) {
      const int grow = (w * 6 + m) * 16 + rr;
      const int wr   = gmap(grow);
      const ushort_t* rp = Wb16 + (size_t)wr * WROW + q * 8;
#pragma unroll
      for (int kt = 0; kt < 8; ++kt) {
        u32x4 v = *(const u32x4*)(rp + kt * 32);
        u32x4 t;
#pragma unroll
        for (int cc = 0; cc < 4; ++cc)
          t[cc] = __builtin_bit_cast(uint_t, bfpair_to_h2(v[cc]));
        wAq[m * 8 + kt] = t;
      }
    }
  } else {
    const float* Wf = (const float*)Wwin;
#pragma unroll
    for (int m = 0; m < 6; ++m) {
      const int grow = (w * 6 + m) * 16 + rr;
      const int wr   = gmap(grow);
      const float* rp = Wf + (size_t)wr * WROW + q * 8;
#pragma unroll
      for (int kt = 0; kt < 8; ++kt) {
        const float* pp = rp + kt * 32;
        float4 a = *(const float4*)(pp);
        float4 b = *(const float4*)(pp + 4);
        h2_t p0, p1, p2, p3;
        p0.x = (_Float16)a.x; p0.y = (_Float16)a.y;
        p1.x = (_Float16)a.z; p1.y = (_Float16)a.w;
        p2.x = (_Float16)b.x; p2.y = (_Float16)b.y;
        p3.x = (_Float16)b.z; p3.y = (_Float16)b.w;
        u32x4 t;
        t[0] = __builtin_bit_cast(uint_t, p0);
        t[1] = __builtin_bit_cast(uint_t, p1);
        t[2] = __builtin_bit_cast(uint_t, p2);
        t[3] = __builtin_bit_cast(uint_t, p3);
        wAq[m * 8 + kt] = t;
      }
    }
  }
  // Un-sinkable residency fences (r16-proven). AGPR-parking is fine: the
  // MFMA below reads AGPR A-operands natively.
  FENCE_V8(wAq);      FENCE_V8(wAq + 8);  FENCE_V8(wAq + 16);
  FENCE_V8(wAq + 24); FENCE_V8(wAq + 32); FENCE_V8(wAq + 40);

  if (tid < 256) hbuf[0][tid] = (_Float16)0.f;   // h_0 = 0

  float c = 0.f, hlast = 0.f;
  const size_t xbase = (size_t)n * L_SEQ;

  // px(t=0), threads 0..255 (j = tid).
  float pxF = 0.f, pxO = 0.f, pxT = 0.f;
  if (tid < 256) {
    int tok0 = x64 ? Xi[xbase * 2] : Xi[xbase];
    if ((uint_t)tok0 >= (uint_t)V_SZ) tok0 = 0;
    const _Float16* e = Eg + (size_t)tok0 * G3 + tid;
    pxF = (float)e[0]; pxO = (float)e[256]; pxT = (float)e[512];
  }

  int cur = 0;
  for (int t = 0; t < L_SEQ; ++t) {
    __syncthreads();  // h(t) published in hbuf[cur]; Gbuf free

    // B-fragments: broadcast h chunks. Lane l reads h[kt*32 + q*8 .. +7];
    // all 16 lanes of a q-group read the same 16B (LDS broadcast).
    u32x4 bfq[8];
#pragma unroll
    for (int kt = 0; kt < 8; ++kt)
      bfq[kt] = *(const u32x4*)&hbuf[cur][kt * 32 + q * 8];

    // Prefetch px(t+1) (threads 0..255), hidden behind the MFMA phase.
    float nF = 0.f, nO = 0.f, nT = 0.f;
    if (tid < 256) {
      int tp = (t + 1 < L_SEQ) ? (t + 1) : (L_SEQ - 1);
      int tok = x64 ? Xi[(xbase + tp) * 2] : Xi[xbase + tp];
      if ((uint_t)tok >= (uint_t)V_SZ) tok = 0;
      const _Float16* e = Eg + (size_t)tok * G3 + tid;
      nF = (float)e[0]; nO = (float)e[256]; nT = (float)e[512];
    }

    // 48 MFMAs: 6 independent accumulator chains x 8 K-steps.
    f32x4 acc[6];
#pragma unroll
    for (int m = 0; m < 6; ++m) acc[m] = f32x4{0.f, 0.f, 0.f, 0.f};
#pragma unroll
    for (int kt = 0; kt < 8; ++kt) {
      f16x8 b = __builtin_bit_cast(f16x8, bfq[kt]);
#pragma unroll
      for (int m = 0; m < 6; ++m) {
        f16x8 a = __builtin_bit_cast(f16x8, wAq[m * 8 + kt]);
        acc[m] = __builtin_amdgcn_mfma_f32_16x16x32_f16(a, b, acc[m], 0, 0, 0);
      }
    }

    // D: col=lane&15 (all equal), row=q*4+reg. Col-0 lanes store G.
    if (rr == 0) {
#pragma unroll
      for (int m = 0; m < 6; ++m)
        *(f32x4*)&Gbuf[(w * 6 + m) * 16 + q * 4] = acc[m];
    }
    __syncthreads();  // G ready

    if (tid < 256) {
      float aF = Gbuf[tid]       + pxF;
      float aO = Gbuf[256 + tid] + pxO;
      float aT = Gbuf[512 + tid] + pxT;
      float Fg = sigmoid_f(aF);
      float Og = sigmoid_f(aO);
      float Tg = tanh_f(aT);
      c = Fg * c + Og * Tg;        // faithful to ref: uses O-gate, not I-gate
      float hv2 = Og * tanh_f(c);
      hlast = hv2;
      hbuf[cur ^ 1][tid] = (_Float16)hv2;   // publish h(t+1)
      pxF = nF; pxO = nO; pxT = nT;
    }
    cur ^= 1;
  }

  // FLOAT32 output, C-order (n, j).
  if (tid < 256) out[(size_t)n * H_DIM + tid] = hlast;
}

extern "C" void kernel_launch(void* const* d_in, const int* in_sizes, int n_in,
                              void* d_out, int out_size, void* d_ws, size_t ws_size,
                              hipStream_t stream) {
  const void* X  = d_in[0];
  const void* E  = d_in[1];
  const void* Ww = d_in[2];
  const void* Wb = d_in[3];
  for (int i = 0; i < n_in && i < 4; ++i) {
    switch (in_sizes[i]) {
      case N_B * L_SEQ: X  = d_in[i]; break;   // 262144
      case V_SZ * EMB:  E  = d_in[i]; break;   // 8192000
      case G4 * WROW:   Ww = d_in[i]; break;   // 524288
      case G4:          Wb = d_in[i]; break;   // 1024
      default: break;
    }
  }
  float* out = (float*)d_out;

  // ws: [0,256) flags | [256, ...) Eg (32000*768 f16 = 46.9 MiB). (= r12)
  uint_t*   flags = (uint_t*)d_ws;
  _Float16* Eg    = (_Float16*)((char*)d_ws + 256);

  dtype_probe<<<dim3(1), dim3(64), 0, stream>>>(
      (const uint_t*)E, (const uint_t*)X, (const uint_t*)Ww, flags);
  eg_gemm<<<dim3(V_SZ / 16), dim3(256), 0, stream>>>(E, Ww, Wb, Eg, flags);
  lstm_rec_mfma<<<dim3(N_B), dim3(512), 0, stream>>>(
      (const int*)X, Ww, Eg, out, flags);
}

// Round 8
// 2966.116 us; speedup vs baseline: 1.4360x; 1.1330x over previous
//
#include <hip/hip_runtime.h>
#include <hip/hip_bf16.h>

// Problem constants (fixed by the harness).
#define N_B   128     // batch
#define L_SEQ 2048    // sequence length
#define H_DIM 256     // hidden
#define EMB   256     // embedding dim
#define G3    768     // 3 used gates (F, O, Htmp) * 256
#define G4    1024    // total gate rows
#define WROW  512     // W_w row length (H + Emb), C-order rows
#define V_SZ  32000   // vocab

// R20: r19 (MFMA formulation, PASSED 6.1e-5, 3.3ms) counter analysis:
// MfmaUtil 21% chip = 42% active-CU => matrix pipe busy ~1620cy of the
// 3870cy step => ~16cy/MFMA at 2 waves/SIMD. The 4.85cy/MFMA ubench rate
// is a MULTI-WAVE interleaved rate; a single wave can't issue MFMAs
// back-to-back at that rate. Fix: 1024 threads (16 waves = 4 waves/SIMD),
// 3 M-tiles/wave. Same 96 MFMA/SIMD/step, 4-way interleave -> phase
// ~450-770cy. Bonus: per-lane weights drop 192->96 dwords (24 frags) --
// naturally fits the hardware-forced 128-reg budget (acc 12 + B transient
// 4 + misc ~15 => ~127). B-frags read per-kt (no 32-reg staging). Eg
// prefetch issued FIRST after barrier1 (max drain coverage to barrier2).
// All layouts/conversions/epilogue/ws verbatim from r19.

typedef unsigned short ushort_t;
typedef unsigned int   uint_t;

using f32x4  = __attribute__((ext_vector_type(4))) float;
using bf16x8 = __attribute__((ext_vector_type(8))) short;
using h2_t   = __attribute__((ext_vector_type(2))) _Float16;
using f16x8  = __attribute__((ext_vector_type(8))) _Float16;
using ushort4_t = __attribute__((ext_vector_type(4))) ushort_t;
using u32x4  = __attribute__((ext_vector_type(4))) uint_t;

__device__ __forceinline__ float bf2f(ushort_t u) {
  union { uint_t u; float f; } x; x.u = ((uint_t)u) << 16; return x.f;
}
__device__ __forceinline__ ushort_t f2bf(float f) {  // RNE f32 -> bf16
  union { float f; uint_t u; } x; x.f = f;
  return (ushort_t)((x.u + 0x7fffu + ((x.u >> 16) & 1u)) >> 16);
}
__device__ __forceinline__ float rcp_f(float x) {
#if __has_builtin(__builtin_amdgcn_rcpf)
  return __builtin_amdgcn_rcpf(x);
#else
  return 1.0f / x;
#endif
}
__device__ __forceinline__ float clampf(float x, float lo, float hi) {
  return fminf(fmaxf(x, lo), hi);
}
__device__ __forceinline__ float sigmoid_f(float x) {
  x = clampf(x, -30.f, 30.f);
  return rcp_f(1.0f + __expf(-x));
}
__device__ __forceinline__ float tanh_f(float x) {
  x = clampf(x, -15.f, 15.f);   // exact: tanh saturates well before 15
  float e = __expf(-2.0f * x);
  return (1.0f - e) * rcp_f(1.0f + e);
}
// bf16 pair (packed dword, little-endian) -> f16 pair (exact for normal range)
__device__ __forceinline__ h2_t bfpair_to_h2(uint_t u) {
  union { uint_t u; float f; } lo, hi;
  lo.u = u << 16;
  hi.u = u & 0xffff0000u;
  h2_t r; r.x = (_Float16)lo.f; r.y = (_Float16)hi.f; return r;
}

// gate col g in [0,768) -> W_w row: F=g, O=512+(g-256), T=768+(g-512)
__device__ __forceinline__ int gmap(int g) { return (g < 256) ? g : g + 256; }

// Volatile fence over 8 x u32x4 (32 dwords): un-sinkable, un-splittable;
// forces simultaneous on-chip residency; values opaque (no remat).
#define FENCE_V8(A) asm volatile("" :                                         \
  "+v"((A)[0]), "+v"((A)[1]), "+v"((A)[2]), "+v"((A)[3]),                     \
  "+v"((A)[4]), "+v"((A)[5]), "+v"((A)[6]), "+v"((A)[7]))

// ---------------------------------------------------------------------------
// Phase 0: dtype probe (validated: r11..r19 passed using these flags).
// ---------------------------------------------------------------------------
__global__ void dtype_probe(const uint_t* __restrict__ Ed,
                            const uint_t* __restrict__ Xd,
                            const uint_t* __restrict__ Wd,
                            uint_t* __restrict__ flags) {
  if (threadIdx.x != 0 || blockIdx.x != 0) return;
  int saneE = 0, saneW = 0;
  for (int i = 0; i < 256; ++i) {
    uint_t le = Ed[i] & 0xffffu, ee = (le >> 7) & 0xffu;
    if (ee == 0u || (ee >= 90u && ee <= 126u)) saneE++;
    uint_t lw = Wd[i] & 0xffffu, ew = (lw >> 7) & 0xffu;
    if (ew == 0u || (ew >= 90u && ew <= 126u)) saneW++;
  }
  uint_t nz = 0u;
  for (int i = 0; i < 128; ++i) nz |= Xd[2 * i + 1];
  flags[0] = (saneE < 192) ? 1u : 0u;   // 1 = f32
  flags[1] = (nz == 0u) ? 1u : 0u;      // 1 = int64
  flags[2] = (saneW < 192) ? 1u : 0u;   // 1 = f32
}

// ---------------------------------------------------------------------------
// Phase 1: Eg[v, g] = sum_k E[v,k] * W_w[gmap(g), 256+k] + W_b[gmap(g)]
// (unchanged from r11 — verified end-to-end, ~tens of µs)
// ---------------------------------------------------------------------------
__global__ __launch_bounds__(256) void eg_gemm(const void* __restrict__ Ein,
                                               const void* __restrict__ Wwin,
                                               const void* __restrict__ Wbin,
                                               _Float16* __restrict__ Eg,
                                               const uint_t* __restrict__ flags) {
  __shared__ __align__(16) ushort_t At[16][264];  // 16 x (256+8 pad) bf16
  const int tid = threadIdx.x;
  const int v0  = blockIdx.x * 16;
  const uint_t ef32 = flags[0];
  const uint_t wf32 = flags[2];

  if (!ef32) {
    const ushort_t* E = (const ushort_t*)Ein;
#pragma unroll
    for (int i = 0; i < 2; ++i) {
      int idx = tid + i * 256;           // 0..511
      int row = idx >> 5, seg = idx & 31;
      const uint4* src = (const uint4*)(E + (size_t)(v0 + row) * EMB + seg * 8);
      *(uint4*)&At[row][seg * 8] = *src;
    }
  } else {
    const float* Ef = (const float*)Ein;
#pragma unroll
    for (int i = 0; i < 4; ++i) {
      int idx = tid + i * 256;           // 0..1023
      int row = idx >> 6, seg = idx & 63;
      float4 v = *(const float4*)(Ef + (size_t)(v0 + row) * EMB + seg * 4);
      ushort4_t s;
      s.x = f2bf(v.x); s.y = f2bf(v.y); s.z = f2bf(v.z); s.w = f2bf(v.w);
      *(ushort4_t*)&At[row][seg * 4] = s;
    }
  }
  __syncthreads();

  const int lane = tid & 63, wv = tid >> 6;
  const int m = lane & 15, q = lane >> 4;

  f32x4 acc[12];
#pragma unroll
  for (int nt = 0; nt < 12; ++nt) acc[nt] = f32x4{0.f, 0.f, 0.f, 0.f};

  if (!wf32) {
    const ushort_t* Ww = (const ushort_t*)Wwin;
#pragma unroll
    for (int kt = 0; kt < 8; ++kt) {
      bf16x8 a = *(const bf16x8*)&At[m][kt * 32 + q * 8];
#pragma unroll
      for (int nt = 0; nt < 12; ++nt) {
        int g  = wv * 192 + nt * 16 + m;
        int gr = gmap(g);
        const bf16x8* bp =
            (const bf16x8*)(Ww + (size_t)gr * WROW + EMB + kt * 32 + q * 8);
        acc[nt] = __builtin_amdgcn_mfma_f32_16x16x32_bf16(a, *bp, acc[nt], 0, 0, 0);
      }
    }
  } else {
    const float* Wf = (const float*)Wwin;
#pragma unroll
    for (int kt = 0; kt < 8; ++kt) {
      bf16x8 a = *(const bf16x8*)&At[m][kt * 32 + q * 8];
#pragma unroll
      for (int nt = 0; nt < 12; ++nt) {
        int g  = wv * 192 + nt * 16 + m;
        int gr = gmap(g);
        const float* wp = Wf + (size_t)gr * WROW + EMB + kt * 32 + q * 8;
        float4 w0 = *(const float4*)(wp);
        float4 w1 = *(const float4*)(wp + 4);
        bf16x8 b;
        b[0] = (short)f2bf(w0.x); b[1] = (short)f2bf(w0.y);
        b[2] = (short)f2bf(w0.z); b[3] = (short)f2bf(w0.w);
        b[4] = (short)f2bf(w1.x); b[5] = (short)f2bf(w1.y);
        b[6] = (short)f2bf(w1.z); b[7] = (short)f2bf(w1.w);
        acc[nt] = __builtin_amdgcn_mfma_f32_16x16x32_bf16(a, b, acc[nt], 0, 0, 0);
      }
    }
  }

#pragma unroll
  for (int nt = 0; nt < 12; ++nt) {
    int g  = wv * 192 + nt * 16 + m;
    int gr = gmap(g);
    float bias = wf32 ? ((const float*)Wbin)[gr] : bf2f(((const ushort_t*)Wbin)[gr]);
#pragma unroll
    for (int j = 0; j < 4; ++j) {
      int v = v0 + q * 4 + j;
      Eg[(size_t)v * G3 + g] = (_Float16)(acc[nt][j] + bias);
    }
  }
}

// ---------------------------------------------------------------------------
// Phase 2 (R20): recurrence via MFMA, 1024 threads (16 waves, 4/SIMD).
// Wave w owns M-tiles 3w..3w+2 (gate rows 48w..48w+47). Per step per wave:
// 24 mfma_f32_16x16x32_f16 (3 chains x 8 kt), B read per-kt from LDS
// (broadcast h chunk). D col=lane&15 (all equal G), row=(lane>>4)*4+reg.
// rr==0 lanes store G; threads 0..255 run the gate/c/h epilogue.
// Per-lane regs: 24 frags (96) + acc 12 + B 4 + misc ~15 => ~127 <= 128
// (hardware-forced at 16 waves). 4-way wave interleave feeds the matrix
// pipe at the multi-wave rate (r19 ran 2 waves/SIMD => ~16cy/MFMA).
// ---------------------------------------------------------------------------
__global__ __launch_bounds__(1024)
void lstm_rec_mfma(const int* __restrict__ Xi,
                   const void* __restrict__ Wwin,
                   const _Float16* __restrict__ Eg,
                   float* __restrict__ out,
                   const uint_t* __restrict__ flags) {
  __shared__ __align__(16) _Float16 hbuf[2][256];  // h(t) as f16
  __shared__ __align__(16) float    Gbuf[G3];      // per-step gate pre-acts
  const int tid  = threadIdx.x;          // 0..1023
  const int lane = tid & 63;
  const int w    = tid >> 6;             // wave 0..15
  const int q    = lane >> 4;            // k-chunk / D-row group
  const int rr   = lane & 15;            // A row within tile
  const int n    = blockIdx.x;
  const uint_t wf32 = flags[2];
  const uint_t x64  = flags[1];

  // ---- Preamble: load 24 A-fragments (f16) DIRECTLY from Wwin. ----
  // Frag (m,kt): lane holds W[(w*3+m)*16 + rr][kt*32 + q*8 .. +7] as f16x8.
  // Conversions identical to r12..r19 (bf16->f16 exact; f32->f16 RNE).
  u32x4 wAq[24];
  if (!wf32) {
    const ushort_t* Wb16 = (const ushort_t*)Wwin;
#pragma unroll
    for (int m = 0; m < 3; ++m) {
      const int grow = (w * 3 + m) * 16 + rr;
      const int wr   = gmap(grow);
      const ushort_t* rp = Wb16 + (size_t)wr * WROW + q * 8;
#pragma unroll
      for (int kt = 0; kt < 8; ++kt) {
        u32x4 v = *(const u32x4*)(rp + kt * 32);
        u32x4 t;
#pragma unroll
        for (int cc = 0; cc < 4; ++cc)
          t[cc] = __builtin_bit_cast(uint_t, bfpair_to_h2(v[cc]));
        wAq[m * 8 + kt] = t;
      }
    }
  } else {
    const float* Wf = (const float*)Wwin;
#pragma unroll
    for (int m = 0; m < 3; ++m) {
      const int grow = (w * 3 + m) * 16 + rr;
      const int wr   = gmap(grow);
      const float* rp = Wf + (size_t)wr * WROW + q * 8;
#pragma unroll
      for (int kt = 0; kt < 8; ++kt) {
        const float* pp = rp + kt * 32;
        float4 a = *(const float4*)(pp);
        float4 b = *(const float4*)(pp + 4);
        h2_t p0, p1, p2, p3;
        p0.x = (_Float16)a.x; p0.y = (_Float16)a.y;
        p1.x = (_Float16)a.z; p1.y = (_Float16)a.w;
        p2.x = (_Float16)b.x; p2.y = (_Float16)b.y;
        p3.x = (_Float16)b.z; p3.y = (_Float16)b.w;
        u32x4 t;
        t[0] = __builtin_bit_cast(uint_t, p0);
        t[1] = __builtin_bit_cast(uint_t, p1);
        t[2] = __builtin_bit_cast(uint_t, p2);
        t[3] = __builtin_bit_cast(uint_t, p3);
        wAq[m * 8 + kt] = t;
      }
    }
  }
  // Un-sinkable residency fences (r16-proven mechanism).
  FENCE_V8(wAq); FENCE_V8(wAq + 8); FENCE_V8(wAq + 16);

  if (tid < 256) hbuf[0][tid] = (_Float16)0.f;   // h_0 = 0

  float c = 0.f, hlast = 0.f;
  const size_t xbase = (size_t)n * L_SEQ;

  // px(t=0), threads 0..255 (j = tid).
  float pxF = 0.f, pxO = 0.f, pxT = 0.f;
  if (tid < 256) {
    int tok0 = x64 ? Xi[xbase * 2] : Xi[xbase];
    if ((uint_t)tok0 >= (uint_t)V_SZ) tok0 = 0;
    const _Float16* e = Eg + (size_t)tok0 * G3 + tid;
    pxF = (float)e[0]; pxO = (float)e[256]; pxT = (float)e[512];
  }

  int cur = 0;
  for (int t = 0; t < L_SEQ; ++t) {
    __syncthreads();  // h(t) published in hbuf[cur]; Gbuf free

    // Eg prefetch ISSUED FIRST: maximum issue->barrier2 distance so the
    // vmcnt drain at barrier2 is covered by the whole MFMA phase.
    float nF = 0.f, nO = 0.f, nT = 0.f;
    if (tid < 256) {
      int tp = (t + 1 < L_SEQ) ? (t + 1) : (L_SEQ - 1);
      int tok = x64 ? Xi[(xbase + tp) * 2] : Xi[xbase + tp];
      if ((uint_t)tok >= (uint_t)V_SZ) tok = 0;
      const _Float16* e = Eg + (size_t)tok * G3 + tid;
      nF = (float)e[0]; nO = (float)e[256]; nT = (float)e[512];
    }

    // 24 MFMAs: 3 independent accumulator chains x 8 K-steps.
    // B per kt: lane reads h[kt*32 + q*8 .. +7] (16B LDS broadcast).
    f32x4 acc0 = f32x4{0.f, 0.f, 0.f, 0.f};
    f32x4 acc1 = f32x4{0.f, 0.f, 0.f, 0.f};
    f32x4 acc2 = f32x4{0.f, 0.f, 0.f, 0.f};
#pragma unroll
    for (int kt = 0; kt < 8; ++kt) {
      f16x8 b = *(const f16x8*)&hbuf[cur][kt * 32 + q * 8];
      acc0 = __builtin_amdgcn_mfma_f32_16x16x32_f16(
          __builtin_bit_cast(f16x8, wAq[kt]),      b, acc0, 0, 0, 0);
      acc1 = __builtin_amdgcn_mfma_f32_16x16x32_f16(
          __builtin_bit_cast(f16x8, wAq[8 + kt]),  b, acc1, 0, 0, 0);
      acc2 = __builtin_amdgcn_mfma_f32_16x16x32_f16(
          __builtin_bit_cast(f16x8, wAq[16 + kt]), b, acc2, 0, 0, 0);
    }

    // D: col=lane&15 (all equal), row=q*4+reg. Col-0 lanes store G.
    if (rr == 0) {
      *(f32x4*)&Gbuf[(w * 3 + 0) * 16 + q * 4] = acc0;
      *(f32x4*)&Gbuf[(w * 3 + 1) * 16 + q * 4] = acc1;
      *(f32x4*)&Gbuf[(w * 3 + 2) * 16 + q * 4] = acc2;
    }
    __syncthreads();  // G ready

    if (tid < 256) {
      float aF = Gbuf[tid]       + pxF;
      float aO = Gbuf[256 + tid] + pxO;
      float aT = Gbuf[512 + tid] + pxT;
      float Fg = sigmoid_f(aF);
      float Og = sigmoid_f(aO);
      float Tg = tanh_f(aT);
      c = Fg * c + Og * Tg;        // faithful to ref: uses O-gate, not I-gate
      float hv2 = Og * tanh_f(c);
      hlast = hv2;
      hbuf[cur ^ 1][tid] = (_Float16)hv2;   // publish h(t+1)
      pxF = nF; pxO = nO; pxT = nT;
    }
    cur ^= 1;
  }

  // FLOAT32 output, C-order (n, j).
  if (tid < 256) out[(size_t)n * H_DIM + tid] = hlast;
}

extern "C" void kernel_launch(void* const* d_in, const int* in_sizes, int n_in,
                              void* d_out, int out_size, void* d_ws, size_t ws_size,
                              hipStream_t stream) {
  const void* X  = d_in[0];
  const void* E  = d_in[1];
  const void* Ww = d_in[2];
  const void* Wb = d_in[3];
  for (int i = 0; i < n_in && i < 4; ++i) {
    switch (in_sizes[i]) {
      case N_B * L_SEQ: X  = d_in[i]; break;   // 262144
      case V_SZ * EMB:  E  = d_in[i]; break;   // 8192000
      case G4 * WROW:   Ww = d_in[i]; break;   // 524288
      case G4:          Wb = d_in[i]; break;   // 1024
      default: break;
    }
  }
  float* out = (float*)d_out;

  // ws: [0,256) flags | [256, ...) Eg (32000*768 f16 = 46.9 MiB). (= r12)
  uint_t*   flags = (uint_t*)d_ws;
  _Float16* Eg    = (_Float16*)((char*)d_ws + 256);

  dtype_probe<<<dim3(1), dim3(64), 0, stream>>>(
      (const uint_t*)E, (const uint_t*)X, (const uint_t*)Ww, flags);
  eg_gemm<<<dim3(V_SZ / 16), dim3(256), 0, stream>>>(E, Ww, Wb, Eg, flags);
  lstm_rec_mfma<<<dim3(N_B), dim3(1024), 0, stream>>>(
      (const int*)X, Ww, Eg, out, flags);
}